// Round 14
// baseline (15.822 us; speedup 1.0000x reference)
//
#include <hip/hip_runtime.h>

#define HH 352
#define WW 1216
#define NBOX 16
#define KCAND 61
#define HN 88    // H/4
#define WN 304   // W/4

#define SLICES 8
#define THREADS 256
#define NWAVE (THREADS / 64)
#define PSTRIDE 128   // per (box,slice): 64 interleaved (W,Q) float pairs:
                      // j<61 -> bin j; j=61 -> (Wlo,Qlo); j=62 -> (Whi,Qhi); j=63 zero

// Kernel 1: kink-histogram (exact O(1)-in-K per pixel).
// |t + k*s| = w*|m - k|, w=|s|, m=-t/s. Interior kinks -> 61 LDS bins
// (W += w, Q += w*m division-free); out-of-range -> register tails.
__global__ void hist_kernel(
    const float* __restrict__ nocs,    // (3, HN, WN)
    const float* __restrict__ dd,      // (HH, WW, 3)
    const int*   __restrict__ boxes,   // (N, 4)
    const float* __restrict__ pc,      // (N, 2)
    const float* __restrict__ bdepth,  // (N,)
    const float* __restrict__ intr,    // (3, 3)
    float* __restrict__ partial,       // (N, S, PSTRIDE)
    int S)
{
    const int slice = blockIdx.x;
    const int box   = blockIdx.y;
    const int tid   = threadIdx.x;

    __shared__ float hW[KCAND];
    __shared__ float hQ[KCAND];
    __shared__ float sred[NWAVE][4];

    if (tid < KCAND) { hW[tid] = 0.f; hQ[tid] = 0.f; }

    const int x1 = boxes[box*4+0], y1 = boxes[box*4+1];
    const int x2 = boxes[box*4+2], y2 = boxes[box*4+3];
    const int bw = x2 - x1;
    const int npix = bw * (y2 - y1);

    const float fx = intr[0], cx = intr[2], fy = intr[4], cy = intr[5];
    const float ax = (pc[box*2+0] - cx) / fx;
    const float ay = (pc[box*2+1] - cy) / fy;
    const float d0 = bdepth[box] - 3.0f;      // candidate depth at k=0

    const float s0 = 0.1f * ax, s1 = 0.1f * ay;
    const float w0 = fabsf(s0), w1 = fabsf(s1), w2 = 0.1f;
    const float ni0 = (w0 > 0.f) ? (-1.0f / s0) : 0.f;
    const float ni1 = (w1 > 0.f) ? (-1.0f / s1) : 0.f;
    const float ni2 = -10.0f;
    const float qf0 = (s0 > 0.f) ? -1.f : 1.f;
    const float qf1 = (s1 > 0.f) ? -1.f : 1.f;
    const float qf2 = -1.f;

    // exact magic-multiply division p/bw (p < 2^15, bw <= 200)
    const unsigned magic = (bw > 1) ? (0xFFFFFFFFu / (unsigned)bw + 1u) : 0u;

    float Wlo = 0.f, Qlo = 0.f, Whi = 0.f, Qhi = 0.f;

    __syncthreads();   // bins zeroed

#define CHANNEL(T_, W_, NI_, QF_)                                          \
    if (W_ > 0.f) {                                                        \
        const float m_  = (T_) * (NI_);                                    \
        const float qv_ = (T_) * (QF_);   /* = w*m, division-free */       \
        if (m_ < 0.f)        { Wlo += W_; Qlo += qv_; }                    \
        else if (m_ < 61.f)  { const int j_ = (int)m_;                     \
                               atomicAdd(&hW[j_], W_);                     \
                               atomicAdd(&hQ[j_], qv_); }                  \
        else                 { Whi += W_; Qhi += qv_; }                    \
    }

    const int stride = S * THREADS;
    for (int p = slice * THREADS + tid; p < npix; p += stride) {
        unsigned q = (bw > 1) ? __umulhi((unsigned)p, magic) : (unsigned)p;
        const int r   = p - (int)q * bw;
        const int row = y1 + (int)q;
        const int x   = x1 + r;

        const float* dp = dd + ((size_t)row * WW + x) * 3;
        const float dz = dp[2];
        const float dp0 = dp[0], dp1 = dp[1];

        const int ry  = row & 3;
        const int yy0 = (row >> 2) + ((ry >= 2) ? 0 : -1);
        const float wy = 0.125f + 0.25f * (float)((ry + 2) & 3);
        const int ya = max(yy0, 0);
        const int yb = min(yy0 + 1, HN - 1);

        const int rx  = x & 3;
        const int xx0 = (x >> 2) + ((rx >= 2) ? 0 : -1);
        const float wx = 0.125f + 0.25f * (float)((rx + 2) & 3);
        const int xa = max(xx0, 0);
        const int xb = min(xx0 + 1, WN - 1);

        float b0, b1, b2;
        {
            const float* n0 = nocs;
            const float* n1 = nocs + (HN * WN);
            const float* n2 = nocs + 2 * (HN * WN);
            const int ia = ya*WN + xa, ib = ya*WN + xb;
            const int ic = yb*WN + xa, id_ = yb*WN + xb;
            const float a00 = n0[ia], a01 = n0[ib], a10 = n0[ic], a11 = n0[id_];
            const float b00 = n1[ia], b01 = n1[ib], b10 = n1[ic], b11 = n1[id_];
            const float c00 = n2[ia], c01 = n2[ib], c10 = n2[ic], c11 = n2[id_];
            const float av0 = a00 + (a01 - a00) * wx, av1 = a10 + (a11 - a10) * wx;
            const float bv0 = b00 + (b01 - b00) * wx, bv1 = b10 + (b11 - b10) * wx;
            const float cv0 = c00 + (c01 - c00) * wx, cv1 = c10 + (c11 - c10) * wx;
            b0 = (av0 + (av1 - av0) * wy) - dp0;
            b1 = (bv0 + (bv1 - bv0) * wy) - dp1;
            b2 = (cv0 + (cv1 - cv0) * wy) - dz;
        }

        if (dz >= 1.0f) {   // empty mask
            const float t0 = fmaf(ax, d0, b0);   // value at k=0 per channel
            const float t1 = fmaf(ay, d0, b1);
            const float t2 = b2 + d0;
            CHANNEL(t0, w0, ni0, qf0)
            CHANNEL(t1, w1, ni1, qf1)
            CHANNEL(t2, w2, ni2, qf2)
        }
    }
#undef CHANNEL

    // block-reduce the 4 register tails
    const int lane = tid & 63;
    const int wave = tid >> 6;
    float r0 = Wlo, r1 = Qlo, r2 = Whi, r3 = Qhi;
    for (int off = 32; off; off >>= 1) {
        r0 += __shfl_xor(r0, off, 64);
        r1 += __shfl_xor(r1, off, 64);
        r2 += __shfl_xor(r2, off, 64);
        r3 += __shfl_xor(r3, off, 64);
    }
    if (lane == 0) {
        sred[wave][0] = r0; sred[wave][1] = r1;
        sred[wave][2] = r2; sred[wave][3] = r3;
    }
    __syncthreads();   // bins (atomics) + sred complete

    float2* pbase = (float2*)(partial + ((size_t)box * S + slice) * PSTRIDE);
    if (tid < KCAND) {
        pbase[tid] = make_float2(hW[tid], hQ[tid]);   // one dwordx2 store
    }
    if (tid == 0) {
        float A = 0.f, B = 0.f, C = 0.f, D = 0.f;
#pragma unroll
        for (int w = 0; w < NWAVE; ++w) {
            A += sred[w][0]; B += sred[w][1];
            C += sred[w][2]; D += sred[w][3];
        }
        pbase[61] = make_float2(A, B);   // (Wlo, Qlo)
        pbase[62] = make_float2(C, D);   // (Whi, Qhi)
        pbase[63] = make_float2(0.f, 0.f);
    }
}

// Kernel 2: per box, lane j sums pair j over slices (float2 loads);
// prefix-scan reconstruction of loss(k); wave argmin; output write.
__global__ __launch_bounds__(64) void finalize_kernel(
    const float* __restrict__ partial,  // (N, S, PSTRIDE)
    const float* __restrict__ pc,
    const float* __restrict__ bdepth,
    const float* __restrict__ dims,     // (N,3)
    const float* __restrict__ intr,
    float* __restrict__ out,            // (N,3)
    int S)
{
    const int box  = blockIdx.x;
    const int lane = threadIdx.x;

    const float2* bp = (const float2*)(partial + (size_t)box * S * PSTRIDE);
    float W = 0.f, Q = 0.f;
#pragma unroll 8
    for (int sl = 0; sl < S; ++sl) {
        const float2 v = bp[(size_t)sl * (PSTRIDE / 2) + lane];
        W += v.x; Q += v.y;
    }

    const float Wlo = __shfl(W, 61, 64), Qlo = __shfl(Q, 61, 64);
    const float Whi = __shfl(W, 62, 64), Qhi = __shfl(Q, 62, 64);

    // inclusive scan over bin lanes
    float sW = (lane < KCAND) ? W : 0.f;
    float sQ = (lane < KCAND) ? Q : 0.f;
    for (int d = 1; d < 64; d <<= 1) {
        const float a = __shfl_up(sW, d, 64);
        const float b = __shfl_up(sQ, d, 64);
        if (lane >= d) { sW += a; sQ += b; }
    }
    const float WT = __shfl(sW, KCAND - 1, 64);
    const float QT = __shfl(sQ, KCAND - 1, 64);
    const float pw = __shfl_up(sW, 1, 64);
    const float pq = __shfl_up(sQ, 1, 64);
    const float PWm1 = (lane == 0) ? 0.f : pw;
    const float PQm1 = (lane == 0) ? 0.f : pq;

    float loss = INFINITY;
    int kk = lane;
    if (lane < KCAND) {
        loss = (float)lane * (Wlo - Whi - WT + 2.f * PWm1)
             + (Qhi - Qlo + QT - 2.f * PQm1);
    }
    // wave argmin, ties -> smaller k (matches jnp.argmin)
    for (int off = 1; off < 64; off <<= 1) {
        const float ol = __shfl_xor(loss, off, 64);
        const int   ok = __shfl_xor(kk,   off, 64);
        if (ol < loss || (ol == loss && ok < kk)) { loss = ol; kk = ok; }
    }
    if (lane == 0) {
        const float fx = intr[0], cx = intr[2], fy = intr[4], cy = intr[5];
        const float dk = bdepth[box] + (0.1f * (float)kk - 3.0f);
        const float axv = (pc[box*2+0] - cx) / fx;
        const float ayv = (pc[box*2+1] - cy) / fy;
        out[box*3+0] = axv * dk;
        out[box*3+1] = ayv * dk + dims[box*3+1] * 0.5f;
        out[box*3+2] = dk;
    }
}

extern "C" void kernel_launch(void* const* d_in, const int* in_sizes, int n_in,
                              void* d_out, int out_size, void* d_ws, size_t ws_size,
                              hipStream_t stream) {
    const float* nocs  = (const float*)d_in[0];
    const float* dd    = (const float*)d_in[1];
    const int*   boxes = (const int*)d_in[2];
    const float* pc    = (const float*)d_in[3];
    const float* bd    = (const float*)d_in[4];
    const float* dims  = (const float*)d_in[5];
    const float* intr  = (const float*)d_in[6];
    float* out     = (float*)d_out;
    float* partial = (float*)d_ws;

    int S = SLICES;
    while (S > 1 && (size_t)NBOX * S * PSTRIDE * sizeof(float) > ws_size) S >>= 1;

    hist_kernel<<<dim3(S, NBOX), THREADS, 0, stream>>>(
        nocs, dd, boxes, pc, bd, intr, partial, S);
    finalize_kernel<<<NBOX, 64, 0, stream>>>(
        partial, pc, bd, dims, intr, out, S);
}

// Round 15
// 13.207 us; speedup vs baseline: 1.1980x; 1.1980x over previous
//
#include <hip/hip_runtime.h>

#define HH 352
#define WW 1216
#define NBOX 16
#define KCAND 61
#define HN 88    // H/4
#define WN 304   // W/4

#define SLICES 16
#define THREADS 256
#define NWAVE (THREADS / 64)
#define PSTRIDE 128   // per (box,slice): 64 interleaved (W,Q) float pairs:
                      // j<61 -> bin j; j=61 -> (Wlo,Qlo); j=62 -> (Whi,Qhi); j=63 zero

// Kernel 1: kink-histogram (exact O(1)-in-K per pixel).
// |t + k*s| = w*|m - k|, w=|s|, m=-t/s. Interior kinks -> 61 LDS bins
// (W += w, Q += w*m division-free); out-of-range -> register tails.
// Grid = 16*16 = 256 blocks (measured optimum: R10/R12/R13/R14 sweep).
__global__ void hist_kernel(
    const float* __restrict__ nocs,    // (3, HN, WN)
    const float* __restrict__ dd,      // (HH, WW, 3)
    const int*   __restrict__ boxes,   // (N, 4)
    const float* __restrict__ pc,      // (N, 2)
    const float* __restrict__ bdepth,  // (N,)
    const float* __restrict__ intr,    // (3, 3)
    float* __restrict__ partial,       // (N, S, PSTRIDE)
    int S)
{
    const int slice = blockIdx.x;
    const int box   = blockIdx.y;
    const int tid   = threadIdx.x;

    __shared__ float hW[KCAND];
    __shared__ float hQ[KCAND];
    __shared__ float sred[NWAVE][4];

    if (tid < KCAND) { hW[tid] = 0.f; hQ[tid] = 0.f; }

    const int x1 = boxes[box*4+0], y1 = boxes[box*4+1];
    const int x2 = boxes[box*4+2], y2 = boxes[box*4+3];
    const int bw = x2 - x1;
    const int npix = bw * (y2 - y1);

    const float fx = intr[0], cx = intr[2], fy = intr[4], cy = intr[5];
    const float ax = (pc[box*2+0] - cx) / fx;
    const float ay = (pc[box*2+1] - cy) / fy;
    const float d0 = bdepth[box] - 3.0f;      // candidate depth at k=0

    const float s0 = 0.1f * ax, s1 = 0.1f * ay;
    const float w0 = fabsf(s0), w1 = fabsf(s1), w2 = 0.1f;
    const float ni0 = (w0 > 0.f) ? (-1.0f / s0) : 0.f;
    const float ni1 = (w1 > 0.f) ? (-1.0f / s1) : 0.f;
    const float ni2 = -10.0f;
    const float qf0 = (s0 > 0.f) ? -1.f : 1.f;
    const float qf1 = (s1 > 0.f) ? -1.f : 1.f;
    const float qf2 = -1.f;

    // exact magic-multiply division p/bw (p < 2^15, bw <= 200)
    const unsigned magic = (bw > 1) ? (0xFFFFFFFFu / (unsigned)bw + 1u) : 0u;

    float Wlo = 0.f, Qlo = 0.f, Whi = 0.f, Qhi = 0.f;

    __syncthreads();   // bins zeroed

#define CHANNEL(T_, W_, NI_, QF_)                                          \
    if (W_ > 0.f) {                                                        \
        const float m_  = (T_) * (NI_);                                    \
        const float qv_ = (T_) * (QF_);   /* = w*m, division-free */       \
        if (m_ < 0.f)        { Wlo += W_; Qlo += qv_; }                    \
        else if (m_ < 61.f)  { const int j_ = (int)m_;                     \
                               atomicAdd(&hW[j_], W_);                     \
                               atomicAdd(&hQ[j_], qv_); }                  \
        else                 { Whi += W_; Qhi += qv_; }                    \
    }

    const int stride = S * THREADS;
    for (int p = slice * THREADS + tid; p < npix; p += stride) {
        unsigned q = (bw > 1) ? __umulhi((unsigned)p, magic) : (unsigned)p;
        const int r   = p - (int)q * bw;
        const int row = y1 + (int)q;
        const int x   = x1 + r;

        const float* dp = dd + ((size_t)row * WW + x) * 3;
        const float dz = dp[2];
        const float dp0 = dp[0], dp1 = dp[1];

        const int ry  = row & 3;
        const int yy0 = (row >> 2) + ((ry >= 2) ? 0 : -1);
        const float wy = 0.125f + 0.25f * (float)((ry + 2) & 3);
        const int ya = max(yy0, 0);
        const int yb = min(yy0 + 1, HN - 1);

        const int rx  = x & 3;
        const int xx0 = (x >> 2) + ((rx >= 2) ? 0 : -1);
        const float wx = 0.125f + 0.25f * (float)((rx + 2) & 3);
        const int xa = max(xx0, 0);
        const int xb = min(xx0 + 1, WN - 1);

        float b0, b1, b2;
        {
            const float* n0 = nocs;
            const float* n1 = nocs + (HN * WN);
            const float* n2 = nocs + 2 * (HN * WN);
            const int ia = ya*WN + xa, ib = ya*WN + xb;
            const int ic = yb*WN + xa, id_ = yb*WN + xb;
            const float a00 = n0[ia], a01 = n0[ib], a10 = n0[ic], a11 = n0[id_];
            const float b00 = n1[ia], b01 = n1[ib], b10 = n1[ic], b11 = n1[id_];
            const float c00 = n2[ia], c01 = n2[ib], c10 = n2[ic], c11 = n2[id_];
            const float av0 = a00 + (a01 - a00) * wx, av1 = a10 + (a11 - a10) * wx;
            const float bv0 = b00 + (b01 - b00) * wx, bv1 = b10 + (b11 - b10) * wx;
            const float cv0 = c00 + (c01 - c00) * wx, cv1 = c10 + (c11 - c10) * wx;
            b0 = (av0 + (av1 - av0) * wy) - dp0;
            b1 = (bv0 + (bv1 - bv0) * wy) - dp1;
            b2 = (cv0 + (cv1 - cv0) * wy) - dz;
        }

        if (dz >= 1.0f) {   // empty mask
            const float t0 = fmaf(ax, d0, b0);   // value at k=0 per channel
            const float t1 = fmaf(ay, d0, b1);
            const float t2 = b2 + d0;
            CHANNEL(t0, w0, ni0, qf0)
            CHANNEL(t1, w1, ni1, qf1)
            CHANNEL(t2, w2, ni2, qf2)
        }
    }
#undef CHANNEL

    // block-reduce the 4 register tails
    const int lane = tid & 63;
    const int wave = tid >> 6;
    float r0 = Wlo, r1 = Qlo, r2 = Whi, r3 = Qhi;
    for (int off = 32; off; off >>= 1) {
        r0 += __shfl_xor(r0, off, 64);
        r1 += __shfl_xor(r1, off, 64);
        r2 += __shfl_xor(r2, off, 64);
        r3 += __shfl_xor(r3, off, 64);
    }
    if (lane == 0) {
        sred[wave][0] = r0; sred[wave][1] = r1;
        sred[wave][2] = r2; sred[wave][3] = r3;
    }
    __syncthreads();   // bins (atomics) + sred complete

    float2* pbase = (float2*)(partial + ((size_t)box * S + slice) * PSTRIDE);
    if (tid < KCAND) {
        pbase[tid] = make_float2(hW[tid], hQ[tid]);   // one dwordx2 store
    }
    if (tid == 0) {
        float A = 0.f, B = 0.f, C = 0.f, D = 0.f;
#pragma unroll
        for (int w = 0; w < NWAVE; ++w) {
            A += sred[w][0]; B += sred[w][1];
            C += sred[w][2]; D += sred[w][3];
        }
        pbase[61] = make_float2(A, B);   // (Wlo, Qlo)
        pbase[62] = make_float2(C, D);   // (Whi, Qhi)
        pbase[63] = make_float2(0.f, 0.f);
    }
}

// Kernel 2: per box, lane j sums pair j over slices (float2 loads);
// prefix-scan reconstruction of loss(k); wave argmin; output write.
__global__ __launch_bounds__(64) void finalize_kernel(
    const float* __restrict__ partial,  // (N, S, PSTRIDE)
    const float* __restrict__ pc,
    const float* __restrict__ bdepth,
    const float* __restrict__ dims,     // (N,3)
    const float* __restrict__ intr,
    float* __restrict__ out,            // (N,3)
    int S)
{
    const int box  = blockIdx.x;
    const int lane = threadIdx.x;

    const float2* bp = (const float2*)(partial + (size_t)box * S * PSTRIDE);
    float W = 0.f, Q = 0.f;
#pragma unroll 16
    for (int sl = 0; sl < S; ++sl) {
        const float2 v = bp[(size_t)sl * (PSTRIDE / 2) + lane];
        W += v.x; Q += v.y;
    }

    const float Wlo = __shfl(W, 61, 64), Qlo = __shfl(Q, 61, 64);
    const float Whi = __shfl(W, 62, 64), Qhi = __shfl(Q, 62, 64);

    // inclusive scan over bin lanes
    float sW = (lane < KCAND) ? W : 0.f;
    float sQ = (lane < KCAND) ? Q : 0.f;
    for (int d = 1; d < 64; d <<= 1) {
        const float a = __shfl_up(sW, d, 64);
        const float b = __shfl_up(sQ, d, 64);
        if (lane >= d) { sW += a; sQ += b; }
    }
    const float WT = __shfl(sW, KCAND - 1, 64);
    const float QT = __shfl(sQ, KCAND - 1, 64);
    const float pw = __shfl_up(sW, 1, 64);
    const float pq = __shfl_up(sQ, 1, 64);
    const float PWm1 = (lane == 0) ? 0.f : pw;
    const float PQm1 = (lane == 0) ? 0.f : pq;

    float loss = INFINITY;
    int kk = lane;
    if (lane < KCAND) {
        loss = (float)lane * (Wlo - Whi - WT + 2.f * PWm1)
             + (Qhi - Qlo + QT - 2.f * PQm1);
    }
    // wave argmin, ties -> smaller k (matches jnp.argmin)
    for (int off = 1; off < 64; off <<= 1) {
        const float ol = __shfl_xor(loss, off, 64);
        const int   ok = __shfl_xor(kk,   off, 64);
        if (ol < loss || (ol == loss && ok < kk)) { loss = ol; kk = ok; }
    }
    if (lane == 0) {
        const float fx = intr[0], cx = intr[2], fy = intr[4], cy = intr[5];
        const float dk = bdepth[box] + (0.1f * (float)kk - 3.0f);
        const float axv = (pc[box*2+0] - cx) / fx;
        const float ayv = (pc[box*2+1] - cy) / fy;
        out[box*3+0] = axv * dk;
        out[box*3+1] = ayv * dk + dims[box*3+1] * 0.5f;
        out[box*3+2] = dk;
    }
}

extern "C" void kernel_launch(void* const* d_in, const int* in_sizes, int n_in,
                              void* d_out, int out_size, void* d_ws, size_t ws_size,
                              hipStream_t stream) {
    const float* nocs  = (const float*)d_in[0];
    const float* dd    = (const float*)d_in[1];
    const int*   boxes = (const int*)d_in[2];
    const float* pc    = (const float*)d_in[3];
    const float* bd    = (const float*)d_in[4];
    const float* dims  = (const float*)d_in[5];
    const float* intr  = (const float*)d_in[6];
    float* out     = (float*)d_out;
    float* partial = (float*)d_ws;

    int S = SLICES;
    while (S > 1 && (size_t)NBOX * S * PSTRIDE * sizeof(float) > ws_size) S >>= 1;

    hist_kernel<<<dim3(S, NBOX), THREADS, 0, stream>>>(
        nocs, dd, boxes, pc, bd, intr, partial, S);
    finalize_kernel<<<NBOX, 64, 0, stream>>>(
        partial, pc, bd, dims, intr, out, S);
}